// Round 7
// baseline (481.532 us; speedup 1.0000x reference)
//
#include <hip/hip_runtime.h>
#include <cstdint>
#include <cstddef>

#define NB 32
#define NN 1024
#define ND 256
#define KNNK 16

// ---------------------------------------------------------------------------
// Kernel A v3: fused positional-add + dual projection GEMM, TRANSPOSED out:
//   Qt [B, 256, 1024], Kt [B, 256, 1024]   (out[e][n] = sum_d h[n][d] w[e][d])
// Tile: 64 e x 64 n, 256 threads, 4x4 microtile. (measured ~85 us)
// ---------------------------------------------------------------------------
__global__ __launch_bounds__(256) void proj_kernel(
    const float* __restrict__ x, const float* __restrict__ pos,
    const float* __restrict__ wq, const float* __restrict__ bq,
    const float* __restrict__ wk, const float* __restrict__ bk,
    float* __restrict__ Qt, float* __restrict__ Kt)
{
    __shared__ __align__(16) float Hs[16][64];   // [d][n_local]
    __shared__ __align__(16) float Ws[16][64];   // [d][e_local]

    const int tid = threadIdx.x;
    const int tx = tid & 15;          // n microtile index
    const int ty = tid >> 4;          // e microtile index
    const int bm = blockIdx.x >> 3;   // 0..511 n tiles (b*16 + ntile)
    const int be = blockIdx.x & 7;    // 0..7 e tiles (0-3 -> Q, 4-7 -> K)
    const int nBase = bm << 6;        // global flattened n base (b*1024 + n0)
    const int b  = nBase >> 10;
    const int n0 = nBase & 1023;
    const int eBase = be << 6;
    const bool isQ = (eBase < 256);
    const float* __restrict__ W    = isQ ? wq : wk;
    const float* __restrict__ bias = isQ ? bq : bk;
    float* __restrict__ Og         = isQ ? Qt : Kt;
    const int e0 = isQ ? eBase : (eBase - 256);

    const int sr = tid >> 2;          // 0..63 (n or e index for staging)
    const int sd = (tid & 3) << 2;    // 0,4,8,12

    float acc[4][4];
    #pragma unroll
    for (int i = 0; i < 4; ++i)
        #pragma unroll
        for (int j = 0; j < 4; ++j) acc[i][j] = 0.0f;

    #pragma unroll 1
    for (int dc = 0; dc < 256; dc += 16) {
        const float4 xv = *(const float4*)&x[(size_t)(nBase + sr) * 256 + dc + sd];
        const float4 pv = *(const float4*)&pos[(size_t)(n0 + sr) * 256 + dc + sd];
        const float4 wv = *(const float4*)&W[(size_t)(e0 + sr) * 256 + dc + sd];
        __syncthreads();   // previous compute done reading LDS
        Hs[sd + 0][sr] = xv.x + pv.x;
        Hs[sd + 1][sr] = xv.y + pv.y;
        Hs[sd + 2][sr] = xv.z + pv.z;
        Hs[sd + 3][sr] = xv.w + pv.w;
        Ws[sd + 0][sr] = wv.x;
        Ws[sd + 1][sr] = wv.y;
        Ws[sd + 2][sr] = wv.z;
        Ws[sd + 3][sr] = wv.w;
        __syncthreads();
        #pragma unroll
        for (int d = 0; d < 16; ++d) {
            const float4 ev = *(const float4*)&Ws[d][ty << 2];   // e-dim (rows)
            const float4 nv = *(const float4*)&Hs[d][tx << 2];   // n-dim (cols)
            const float a4[4] = {ev.x, ev.y, ev.z, ev.w};
            const float b4[4] = {nv.x, nv.y, nv.z, nv.w};
            #pragma unroll
            for (int i = 0; i < 4; ++i)
                #pragma unroll
                for (int j = 0; j < 4; ++j)
                    acc[i][j] = fmaf(a4[i], b4[j], acc[i][j]);
        }
    }

    const float4 bv4 = *(const float4*)&bias[e0 + (ty << 2)];
    const float bb[4] = {bv4.x, bv4.y, bv4.z, bv4.w};
    #pragma unroll
    for (int i = 0; i < 4; ++i)
        #pragma unroll
        for (int j = 0; j < 4; ++j) acc[i][j] += bb[i];

    // coalesced transposed stores: row e = e0+4ty+i, cols n0+4tx..+3
    #pragma unroll
    for (int i = 0; i < 4; ++i) {
        float4 o;
        o.x = acc[i][0]; o.y = acc[i][1]; o.z = acc[i][2]; o.w = acc[i][3];
        *(float4*)&Og[(size_t)((b << 8) + e0 + (ty << 2) + i) * 1024 + n0 + (tx << 2)] = o;
    }
}

// ---------------------------------------------------------------------------
// Kernel B v7: scores + softmax + top-16, fused.
// One WG = (batch b, 16 rows), 256 threads = 4 waves; wave w owns cols
// [256w, 256w+256), lane owns 4 adjacent cols -> acc[16][4] = 64 VGPRs.
// v7 changes vs v6 (scratch spill: WRITE 390MB vs 134 ideal, VGPR_Count 52
// << acc footprint, launch_bounds cap 128 exceeded at epilogue peak):
//  - 16-row blocks: acc 64 regs; main-loop peak ~100 regs.
//  - Epilogue: 4 passes x 4 rows via Sc[4][1024] (16KB, ALIASES Qlds);
//    one row per wave; only ONE mutable wv[16] (mx/ls streamed from it,
//    final write re-reads Sc -> bit-identical). Peak ~85 regs.
//  - Q staged once in LDS [256][16], broadcast ds_read_b128.
//  - Bijective XCD swizzle: each XCD owns 4 contiguous batches.
// Verification targets: WRITE_SIZE == 131072 KB exactly, VGPR_Count ~100+.
// ---------------------------------------------------------------------------
__global__ __launch_bounds__(256, 4) void adj_topk_kernel(
    const float* __restrict__ Qt, const float* __restrict__ Kt,
    float* __restrict__ out)
{
    __shared__ __align__(16) float SB[4096];      // 16 KB, dual-purpose
    float (*Qlds)[16]  = (float(*)[16])SB;        // [256][16] main loop
    float (*Sc)[1024]  = (float(*)[1024])SB;      // [4][1024]  epilogue

    const int tid  = threadIdx.x;
    const int lane = tid & 63;
    const int w    = tid >> 6;                    // 0..3
    const int bid  = ((blockIdx.x & 7) << 8) + (blockIdx.x >> 3);  // XCD swizzle
    const int b       = bid >> 6;
    const int rowBase = (bid & 63) << 4;

    const float* __restrict__ Qb = Qt + (size_t)b * (256 * 1024) + rowBase;
    const float* __restrict__ kp = Kt + (size_t)b * (256 * 1024) + (w << 8) + (lane << 2);

    // ---- stage Q tile into LDS: Qlds[d][r] = Qb[d*1024 + r], r<16 ----
    {
        const int d0 = tid >> 2;              // 0..63
        const int rc = (tid & 3) << 2;        // 0,4,8,12
        #pragma unroll
        for (int p = 0; p < 4; ++p) {
            const int d = d0 + (p << 6);
            *(float4*)&Qlds[d][rc] = *(const float4*)&Qb[(size_t)d * 1024 + rc];
        }
    }
    __syncthreads();

    float acc[16][4];
    #pragma unroll
    for (int r = 0; r < 16; ++r)
        #pragma unroll
        for (int c = 0; c < 4; ++c) acc[r][c] = 0.0f;

    // ---- prefetch K for d=0,1 ----
    float4 k0 = *(const float4*)&kp[0];
    float4 k1 = *(const float4*)&kp[1024];

    // ---- main loop: 128 chunks of 2 d-steps, barrier-free ----
    #pragma unroll 2
    for (int d = 0; d < 256; d += 2) {
        const int dn = (d + 2) & 255;          // wrap: final prefetch harmless
        const float4 kn0 = *(const float4*)&kp[(size_t)dn * 1024];
        const float4 kn1 = *(const float4*)&kp[(size_t)(dn + 1) * 1024];

        #pragma unroll
        for (int g = 0; g < 4; ++g) {
            const float4 q0 = *(const float4*)&Qlds[d][g << 2];      // broadcast
            const float4 q1 = *(const float4*)&Qlds[d + 1][g << 2];  // broadcast
            const float q0a[4] = {q0.x, q0.y, q0.z, q0.w};
            const float q1a[4] = {q1.x, q1.y, q1.z, q1.w};
            #pragma unroll
            for (int j = 0; j < 4; ++j) {
                const int r = (g << 2) + j;
                acc[r][0] = fmaf(q0a[j], k0.x, acc[r][0]);
                acc[r][1] = fmaf(q0a[j], k0.y, acc[r][1]);
                acc[r][2] = fmaf(q0a[j], k0.z, acc[r][2]);
                acc[r][3] = fmaf(q0a[j], k0.w, acc[r][3]);
                acc[r][0] = fmaf(q1a[j], k1.x, acc[r][0]);
                acc[r][1] = fmaf(q1a[j], k1.y, acc[r][1]);
                acc[r][2] = fmaf(q1a[j], k1.z, acc[r][2]);
                acc[r][3] = fmaf(q1a[j], k1.w, acc[r][3]);
            }
        }
        k0 = kn0;
        k1 = kn1;
    }

    // ---- epilogue: 4 passes of 4 rows; Sc aliases Qlds (sync-guarded) ----
    const int growBase = b * 1024 + rowBase;

    #pragma unroll 1
    for (int p = 0; p < 4; ++p) {
        __syncthreads();            // Qlds reads / prior pass reads complete
        #pragma unroll
        for (int rr = 0; rr < 4; ++rr) {
            float4 v;
            v.x = acc[(p << 2) + rr][0];
            v.y = acc[(p << 2) + rr][1];
            v.z = acc[(p << 2) + rr][2];
            v.w = acc[(p << 2) + rr][3];
            *(float4*)&Sc[rr][(w << 8) + (lane << 2)] = v;
        }
        __syncthreads();

        // wave w selects row rowBase + 4p + w; working copy wv[16] only
        float wv[16];
        #pragma unroll
        for (int o = 0; o < 4; ++o) {
            const float4 sv = *(const float4*)&Sc[w][(o << 8) + (lane << 2)];
            wv[(o << 2) + 0] = sv.x * 0.0625f;
            wv[(o << 2) + 1] = sv.y * 0.0625f;
            wv[(o << 2) + 2] = sv.z * 0.0625f;
            wv[(o << 2) + 3] = sv.w * 0.0625f;
        }

        // row max (wave butterfly)
        float mx = wv[0];
        #pragma unroll
        for (int i = 1; i < 16; ++i) mx = fmaxf(mx, wv[i]);
        #pragma unroll
        for (int off = 32; off > 0; off >>= 1)
            mx = fmaxf(mx, __shfl_xor(mx, off));

        // softmax denominator
        float ls = 0.f;
        #pragma unroll
        for (int i = 0; i < 16; ++i) ls += __expf(wv[i] - mx);
        #pragma unroll
        for (int off = 32; off > 0; off >>= 1)
            ls += __shfl_xor(ls, off);
        const float rZ = 1.0f / ls;

        // top-16 extraction (destroys wv); winners -> bitmask
        unsigned mask = 0u;
        #pragma unroll 1
        for (int j = 0; j < KNNK; ++j) {
            float bv  = wv[0];
            int   bsi = 0;
            #pragma unroll
            for (int i = 1; i < 16; ++i) {
                const bool c = wv[i] > bv;   // strict >, ascending slot scan
                bv  = c ? wv[i] : bv;
                bsi = c ? i     : bsi;
            }
            const int bmi = ((bsi >> 2) << 8) + (lane << 2) + (bsi & 3);
            const unsigned ub   = __float_as_uint(bv);
            const unsigned mono = ub ^ (unsigned)(((int)ub >> 31) | 0x80000000);
            const unsigned long long key =
                ((unsigned long long)mono << 32) | (unsigned)(~bmi);
            unsigned long long gk = key;
            #pragma unroll
            for (int off = 32; off > 0; off >>= 1) {
                const unsigned long long o = __shfl_xor(gk, off);
                gk = (o > gk) ? o : gk;
            }
            if (key == gk) {                 // unique winner lane
                mask |= (1u << bsi);
                #pragma unroll
                for (int i = 0; i < 16; ++i)
                    wv[i] = (i == bsi) ? -__builtin_inff() : wv[i];
            }
        }

        // full-coverage coalesced write; values re-read from Sc (bit-identical)
        float* orow = out + ((size_t)(growBase + (p << 2) + w)) * 1024;
        #pragma unroll
        for (int o = 0; o < 4; ++o) {
            const float4 sv = *(const float4*)&Sc[w][(o << 8) + (lane << 2)];
            float4 v;
            v.x = ((mask >> ((o << 2) + 0)) & 1u) ? __expf(sv.x * 0.0625f - mx) * rZ : 0.f;
            v.y = ((mask >> ((o << 2) + 1)) & 1u) ? __expf(sv.y * 0.0625f - mx) * rZ : 0.f;
            v.z = ((mask >> ((o << 2) + 2)) & 1u) ? __expf(sv.z * 0.0625f - mx) * rZ : 0.f;
            v.w = ((mask >> ((o << 2) + 3)) & 1u) ? __expf(sv.w * 0.0625f - mx) * rZ : 0.f;
            *(float4*)&orow[(lane << 2) + (o << 8)] = v;
        }
    }
}

extern "C" void kernel_launch(void* const* d_in, const int* in_sizes, int n_in,
                              void* d_out, int out_size, void* d_ws, size_t ws_size,
                              hipStream_t stream)
{
    const float* x   = (const float*)d_in[0];
    const float* pos = (const float*)d_in[1];
    const float* wq  = (const float*)d_in[2];
    const float* bq  = (const float*)d_in[3];
    const float* wk  = (const float*)d_in[4];
    const float* bk  = (const float*)d_in[5];
    float* out = (float*)d_out;

    float* Qt = (float*)d_ws;                    // 32 MB: [B, 256, 1024]
    float* Kt = Qt + (size_t)NB * NN * ND;       // 32 MB: [B, 256, 1024]

    proj_kernel<<<dim3(4096), dim3(256), 0, stream>>>(x, pos, wq, bq, wk, bk, Qt, Kt);
    adj_topk_kernel<<<dim3(2048), dim3(256), 0, stream>>>(Qt, Kt, out);
}

// Round 8
// 447.229 us; speedup vs baseline: 1.0767x; 1.0767x over previous
//
#include <hip/hip_runtime.h>
#include <cstdint>
#include <cstddef>

#define NB 32
#define NN 1024
#define ND 256
#define KNNK 16

// ---------------------------------------------------------------------------
// Kernel A v3: fused positional-add + dual projection GEMM, TRANSPOSED out:
//   Qt [B, 256, 1024], Kt [B, 256, 1024]   (out[e][n] = sum_d h[n][d] w[e][d])
// Tile: 64 e x 64 n, 256 threads, 4x4 microtile. (measured ~85 us)
// ---------------------------------------------------------------------------
__global__ __launch_bounds__(256) void proj_kernel(
    const float* __restrict__ x, const float* __restrict__ pos,
    const float* __restrict__ wq, const float* __restrict__ bq,
    const float* __restrict__ wk, const float* __restrict__ bk,
    float* __restrict__ Qt, float* __restrict__ Kt)
{
    __shared__ __align__(16) float Hs[16][64];   // [d][n_local]
    __shared__ __align__(16) float Ws[16][64];   // [d][e_local]

    const int tid = threadIdx.x;
    const int tx = tid & 15;          // n microtile index
    const int ty = tid >> 4;          // e microtile index
    const int bm = blockIdx.x >> 3;   // 0..511 n tiles (b*16 + ntile)
    const int be = blockIdx.x & 7;    // 0..7 e tiles (0-3 -> Q, 4-7 -> K)
    const int nBase = bm << 6;        // global flattened n base (b*1024 + n0)
    const int b  = nBase >> 10;
    const int n0 = nBase & 1023;
    const int eBase = be << 6;
    const bool isQ = (eBase < 256);
    const float* __restrict__ W    = isQ ? wq : wk;
    const float* __restrict__ bias = isQ ? bq : bk;
    float* __restrict__ Og         = isQ ? Qt : Kt;
    const int e0 = isQ ? eBase : (eBase - 256);

    const int sr = tid >> 2;          // 0..63 (n or e index for staging)
    const int sd = (tid & 3) << 2;    // 0,4,8,12

    float acc[4][4];
    #pragma unroll
    for (int i = 0; i < 4; ++i)
        #pragma unroll
        for (int j = 0; j < 4; ++j) acc[i][j] = 0.0f;

    #pragma unroll 1
    for (int dc = 0; dc < 256; dc += 16) {
        const float4 xv = *(const float4*)&x[(size_t)(nBase + sr) * 256 + dc + sd];
        const float4 pv = *(const float4*)&pos[(size_t)(n0 + sr) * 256 + dc + sd];
        const float4 wv = *(const float4*)&W[(size_t)(e0 + sr) * 256 + dc + sd];
        __syncthreads();   // previous compute done reading LDS
        Hs[sd + 0][sr] = xv.x + pv.x;
        Hs[sd + 1][sr] = xv.y + pv.y;
        Hs[sd + 2][sr] = xv.z + pv.z;
        Hs[sd + 3][sr] = xv.w + pv.w;
        Ws[sd + 0][sr] = wv.x;
        Ws[sd + 1][sr] = wv.y;
        Ws[sd + 2][sr] = wv.z;
        Ws[sd + 3][sr] = wv.w;
        __syncthreads();
        #pragma unroll
        for (int d = 0; d < 16; ++d) {
            const float4 ev = *(const float4*)&Ws[d][ty << 2];   // e-dim (rows)
            const float4 nv = *(const float4*)&Hs[d][tx << 2];   // n-dim (cols)
            const float a4[4] = {ev.x, ev.y, ev.z, ev.w};
            const float b4[4] = {nv.x, nv.y, nv.z, nv.w};
            #pragma unroll
            for (int i = 0; i < 4; ++i)
                #pragma unroll
                for (int j = 0; j < 4; ++j)
                    acc[i][j] = fmaf(a4[i], b4[j], acc[i][j]);
        }
    }

    const float4 bv4 = *(const float4*)&bias[e0 + (ty << 2)];
    const float bb[4] = {bv4.x, bv4.y, bv4.z, bv4.w};
    #pragma unroll
    for (int i = 0; i < 4; ++i)
        #pragma unroll
        for (int j = 0; j < 4; ++j) acc[i][j] += bb[i];

    // coalesced transposed stores: row e = e0+4ty+i, cols n0+4tx..+3
    #pragma unroll
    for (int i = 0; i < 4; ++i) {
        float4 o;
        o.x = acc[i][0]; o.y = acc[i][1]; o.z = acc[i][2]; o.w = acc[i][3];
        *(float4*)&Og[(size_t)((b << 8) + e0 + (ty << 2) + i) * 1024 + n0 + (tx << 2)] = o;
    }
}

// ---------------------------------------------------------------------------
// Kernel B v8: scores + softmax + top-16, fused.
// One WG = (batch b, 16 rows), 256 threads = 4 waves; wave w owns cols
// [256w, 256w+256), lane owns 4 adjacent cols -> acc[16][4] = 64 VGPRs.
//
// v8 change vs v7 (THE spill bug): v5-v7's epilogue pass loop was
// `#pragma unroll 1`, making acc[(p<<2)+rr] a RUNTIME-indexed register
// array -> whole accumulator allocated in scratch (rule: runtime-indexed
// ext_vector/arrays go to local memory). Evidence: WRITE_SIZE 378880 KB
// (= 131072 ideal + ~acc dump/reload), VGPR_Count 56 < acc footprint.
// Fix: FULLY UNROLL the pass loop -> all acc indices compile-time.
// Verification targets: WRITE_SIZE == 131072 KB exactly, VGPR_Count ~110.
// ---------------------------------------------------------------------------
__global__ __launch_bounds__(256, 4) void adj_topk_kernel(
    const float* __restrict__ Qt, const float* __restrict__ Kt,
    float* __restrict__ out)
{
    __shared__ __align__(16) float SB[4096];      // 16 KB, dual-purpose
    float (*Qlds)[16]  = (float(*)[16])SB;        // [256][16] main loop
    float (*Sc)[1024]  = (float(*)[1024])SB;      // [4][1024]  epilogue

    const int tid  = threadIdx.x;
    const int lane = tid & 63;
    const int w    = tid >> 6;                    // 0..3
    const int bid  = ((blockIdx.x & 7) << 8) + (blockIdx.x >> 3);  // XCD swizzle
    const int b       = bid >> 6;
    const int rowBase = (bid & 63) << 4;

    const float* __restrict__ Qb = Qt + (size_t)b * (256 * 1024) + rowBase;
    const float* __restrict__ kp = Kt + (size_t)b * (256 * 1024) + (w << 8) + (lane << 2);

    // ---- stage Q tile into LDS: Qlds[d][r] = Qb[d*1024 + r], r<16 ----
    {
        const int d0 = tid >> 2;              // 0..63
        const int rc = (tid & 3) << 2;        // 0,4,8,12
        #pragma unroll
        for (int p = 0; p < 4; ++p) {
            const int d = d0 + (p << 6);
            *(float4*)&Qlds[d][rc] = *(const float4*)&Qb[(size_t)d * 1024 + rc];
        }
    }
    __syncthreads();

    float acc[16][4];
    #pragma unroll
    for (int r = 0; r < 16; ++r)
        #pragma unroll
        for (int c = 0; c < 4; ++c) acc[r][c] = 0.0f;

    // ---- prefetch K for d=0,1 ----
    float4 k0 = *(const float4*)&kp[0];
    float4 k1 = *(const float4*)&kp[1024];

    // ---- main loop: 128 chunks of 2 d-steps, barrier-free ----
    #pragma unroll 2
    for (int d = 0; d < 256; d += 2) {
        const int dn = (d + 2) & 255;          // wrap: final prefetch harmless
        const float4 kn0 = *(const float4*)&kp[(size_t)dn * 1024];
        const float4 kn1 = *(const float4*)&kp[(size_t)(dn + 1) * 1024];

        #pragma unroll
        for (int g = 0; g < 4; ++g) {
            const float4 q0 = *(const float4*)&Qlds[d][g << 2];      // broadcast
            const float4 q1 = *(const float4*)&Qlds[d + 1][g << 2];  // broadcast
            const float q0a[4] = {q0.x, q0.y, q0.z, q0.w};
            const float q1a[4] = {q1.x, q1.y, q1.z, q1.w};
            #pragma unroll
            for (int j = 0; j < 4; ++j) {
                const int r = (g << 2) + j;
                acc[r][0] = fmaf(q0a[j], k0.x, acc[r][0]);
                acc[r][1] = fmaf(q0a[j], k0.y, acc[r][1]);
                acc[r][2] = fmaf(q0a[j], k0.z, acc[r][2]);
                acc[r][3] = fmaf(q0a[j], k0.w, acc[r][3]);
                acc[r][0] = fmaf(q1a[j], k1.x, acc[r][0]);
                acc[r][1] = fmaf(q1a[j], k1.y, acc[r][1]);
                acc[r][2] = fmaf(q1a[j], k1.z, acc[r][2]);
                acc[r][3] = fmaf(q1a[j], k1.w, acc[r][3]);
            }
        }
        k0 = kn0;
        k1 = kn1;
    }

    // ---- epilogue: 4 passes of 4 rows, FULLY UNROLLED (static acc idx) ----
    const int growBase = b * 1024 + rowBase;

    #pragma unroll
    for (int p = 0; p < 4; ++p) {     // FULL unroll: p is compile-time
        __syncthreads();              // Qlds reads / prior pass reads complete
        #pragma unroll
        for (int rr = 0; rr < 4; ++rr) {
            float4 v;
            v.x = acc[(p << 2) + rr][0];
            v.y = acc[(p << 2) + rr][1];
            v.z = acc[(p << 2) + rr][2];
            v.w = acc[(p << 2) + rr][3];
            *(float4*)&Sc[rr][(w << 8) + (lane << 2)] = v;
        }
        __syncthreads();

        // wave w selects row rowBase + 4p + w; working copy wv[16] only
        float wv[16];
        #pragma unroll
        for (int o = 0; o < 4; ++o) {
            const float4 sv = *(const float4*)&Sc[w][(o << 8) + (lane << 2)];
            wv[(o << 2) + 0] = sv.x * 0.0625f;
            wv[(o << 2) + 1] = sv.y * 0.0625f;
            wv[(o << 2) + 2] = sv.z * 0.0625f;
            wv[(o << 2) + 3] = sv.w * 0.0625f;
        }

        // row max (wave butterfly)
        float mx = wv[0];
        #pragma unroll
        for (int i = 1; i < 16; ++i) mx = fmaxf(mx, wv[i]);
        #pragma unroll
        for (int off = 32; off > 0; off >>= 1)
            mx = fmaxf(mx, __shfl_xor(mx, off));

        // softmax denominator
        float ls = 0.f;
        #pragma unroll
        for (int i = 0; i < 16; ++i) ls += __expf(wv[i] - mx);
        #pragma unroll
        for (int off = 32; off > 0; off >>= 1)
            ls += __shfl_xor(ls, off);
        const float rZ = 1.0f / ls;

        // top-16 extraction (destroys wv); winners -> bitmask
        unsigned mask = 0u;
        #pragma unroll 1
        for (int j = 0; j < KNNK; ++j) {
            float bv  = wv[0];
            int   bsi = 0;
            #pragma unroll
            for (int i = 1; i < 16; ++i) {
                const bool c = wv[i] > bv;   // strict >, ascending slot scan
                bv  = c ? wv[i] : bv;
                bsi = c ? i     : bsi;
            }
            const int bmi = ((bsi >> 2) << 8) + (lane << 2) + (bsi & 3);
            const unsigned ub   = __float_as_uint(bv);
            const unsigned mono = ub ^ (unsigned)(((int)ub >> 31) | 0x80000000);
            const unsigned long long key =
                ((unsigned long long)mono << 32) | (unsigned)(~bmi);
            unsigned long long gk = key;
            #pragma unroll
            for (int off = 32; off > 0; off >>= 1) {
                const unsigned long long o = __shfl_xor(gk, off);
                gk = (o > gk) ? o : gk;
            }
            if (key == gk) {                 // unique winner lane
                mask |= (1u << bsi);
                #pragma unroll
                for (int i = 0; i < 16; ++i)
                    wv[i] = (i == bsi) ? -__builtin_inff() : wv[i];
            }
        }

        // full-coverage coalesced write; values re-read from Sc (bit-identical)
        float* orow = out + ((size_t)(growBase + (p << 2) + w)) * 1024;
        #pragma unroll
        for (int o = 0; o < 4; ++o) {
            const float4 sv = *(const float4*)&Sc[w][(o << 8) + (lane << 2)];
            float4 v;
            v.x = ((mask >> ((o << 2) + 0)) & 1u) ? __expf(sv.x * 0.0625f - mx) * rZ : 0.f;
            v.y = ((mask >> ((o << 2) + 1)) & 1u) ? __expf(sv.y * 0.0625f - mx) * rZ : 0.f;
            v.z = ((mask >> ((o << 2) + 2)) & 1u) ? __expf(sv.z * 0.0625f - mx) * rZ : 0.f;
            v.w = ((mask >> ((o << 2) + 3)) & 1u) ? __expf(sv.w * 0.0625f - mx) * rZ : 0.f;
            *(float4*)&orow[(lane << 2) + (o << 8)] = v;
        }
    }
}

extern "C" void kernel_launch(void* const* d_in, const int* in_sizes, int n_in,
                              void* d_out, int out_size, void* d_ws, size_t ws_size,
                              hipStream_t stream)
{
    const float* x   = (const float*)d_in[0];
    const float* pos = (const float*)d_in[1];
    const float* wq  = (const float*)d_in[2];
    const float* bq  = (const float*)d_in[3];
    const float* wk  = (const float*)d_in[4];
    const float* bk  = (const float*)d_in[5];
    float* out = (float*)d_out;

    float* Qt = (float*)d_ws;                    // 32 MB: [B, 256, 1024]
    float* Kt = Qt + (size_t)NB * NN * ND;       // 32 MB: [B, 256, 1024]

    proj_kernel<<<dim3(4096), dim3(256), 0, stream>>>(x, pos, wq, bq, wk, bk, Qt, Kt);
    adj_topk_kernel<<<dim3(2048), dim3(256), 0, stream>>>(Qt, Kt, out);
}